// Round 2
// baseline (118.148 us; speedup 1.0000x reference)
//
#include <hip/hip_runtime.h>
#include <cfloat>
#include <cstddef>

#define NBATCH 2
#define NPTS   5000
#define NF     64
#define NB     10      // bins = N / BIN_SIZE
#define BINSZ  500
#define TOPK   5
#define ROTCOLS 100    // MAX_NUM_BINS/2 columns in rotations
#define ROW4   (NPTS / 4)   // 1250 float4 per output row

// ---------------------------------------------------------------------------
// Kernel A: per-point LSH bin + squared norm. One wave (64 lanes) per point.
// ---------------------------------------------------------------------------
__global__ __launch_bounds__(256) void bin_norm_k(const float* __restrict__ pts,
                                                  const float* __restrict__ rot,
                                                  int* __restrict__ bin_idx,
                                                  float* __restrict__ na) {
    int pt   = blockIdx.x * 4 + (threadIdx.x >> 6);
    int lane = threadIdx.x & 63;
    float p  = pts[(size_t)pt * NF + lane];
    float nn = p * p;
    float c0 = p * rot[lane * ROTCOLS + 0];
    float c1 = p * rot[lane * ROTCOLS + 1];
    float c2 = p * rot[lane * ROTCOLS + 2];
    float c3 = p * rot[lane * ROTCOLS + 3];
    float c4 = p * rot[lane * ROTCOLS + 4];
    #pragma unroll
    for (int off = 32; off > 0; off >>= 1) {
        nn += __shfl_xor(nn, off);
        c0 += __shfl_xor(c0, off);
        c1 += __shfl_xor(c1, off);
        c2 += __shfl_xor(c2, off);
        c3 += __shfl_xor(c3, off);
        c4 += __shfl_xor(c4, off);
    }
    if (lane == 0) {
        float c[5] = {c0, c1, c2, c3, c4};
        float bv = c[0]; int bi = 0;
        #pragma unroll
        for (int h = 1; h < 5; ++h) if (c[h] > bv) { bv = c[h]; bi = h; }
        #pragma unroll
        for (int h = 0; h < 5; ++h) if (-c[h] > bv) { bv = -c[h]; bi = h + 5; }
        bin_idx[pt] = bi;   // first-max wins, matches jnp.argmax
        na[pt] = nn;
    }
}

// ---------------------------------------------------------------------------
// Kernel B: stable counting sort of point indices by bin. One block per batch.
// ---------------------------------------------------------------------------
__global__ __launch_bounds__(256) void sort_k(const int* __restrict__ bin_idx,
                                              int* __restrict__ order) {
    const int b = blockIdx.x;
    const int t = threadIdx.x;
    __shared__ int sh_bin[NPTS];
    __shared__ int sh_hist[256][NB];
    __shared__ int sh_start[NB + 1];
    for (int i = t; i < NPTS; i += 256) sh_bin[i] = bin_idx[b * NPTS + i];
    #pragma unroll
    for (int h = 0; h < NB; ++h) sh_hist[t][h] = 0;
    __syncthreads();
    const int CH = (NPTS + 255) / 256;            // 20
    const int i0 = t * CH;
    const int i1 = (i0 + CH < NPTS) ? (i0 + CH) : NPTS;
    for (int i = i0; i < i1; ++i) sh_hist[t][sh_bin[i]]++;
    __syncthreads();
    if (t < NB) {
        int tot = 0;
        for (int c = 0; c < 256; ++c) tot += sh_hist[c][t];
        sh_start[t + 1] = tot;
    }
    __syncthreads();
    if (t == 0) {
        sh_start[0] = 0;
        for (int h = 1; h <= NB; ++h) sh_start[h] += sh_start[h - 1];
    }
    __syncthreads();
    if (t < NB) {
        int run = sh_start[t];
        for (int c = 0; c < 256; ++c) { int v = sh_hist[c][t]; sh_hist[c][t] = run; run += v; }
    }
    __syncthreads();
    for (int i = i0; i < i1; ++i) {
        int h = sh_bin[i];
        order[b * NPTS + sh_hist[t][h]++] = i;
    }
}

// ---------------------------------------------------------------------------
// Kernel C: per-group pairwise d^2 + top-5 + FUSED row zero-fill + scatter.
// Grid: 20 groups x 8 row-blocks = 160 blocks of 256 threads.
// Each block owns 64 output rows exclusively: it streams 64x5000 zeros
// (float4, coalesced) interleaved with the gram/top-k compute so the write
// drain hides the VALU work, then (after a barrier that drains vmcnt)
// overwrites the 5 winner positions per row. No memset kernel needed.
// ---------------------------------------------------------------------------
__global__ __launch_bounds__(256) void pair_topk_k(const float* __restrict__ pts,
                                                   const float* __restrict__ na,
                                                   const int* __restrict__ order,
                                                   float* __restrict__ out) {
    const int bx  = blockIdx.x;
    const int g   = bx >> 3;        // 0..19
    const int rb  = bx & 7;         // 0..7 (row block of 64)
    const int b   = g / NB;
    const int grp = g % NB;
    const int r0  = rb * 64;
    const int tid = threadIdx.x;
    const int w   = tid >> 6;       // col partition 0..3
    const int lane = tid & 63;      // row within block

    __shared__ float sh_pts[BINSZ * NF];     // 128000 B
    __shared__ float sh_na[BINSZ];
    __shared__ int   sh_idx[BINSZ];
    __shared__ float sh_mv[4][64][TOPK];
    __shared__ int   sh_mi[4][64][TOPK];

    const int* ord = order + b * NPTS + grp * BINSZ;
    for (int i = tid; i < BINSZ; i += 256) sh_idx[i] = ord[i];
    __syncthreads();

    const float* pbase = pts + (size_t)b * NPTS * NF;
    float4* sp4 = (float4*)sh_pts;
    for (int q = tid; q < BINSZ * (NF / 4); q += 256) {
        int j = q >> 4, f4 = q & 15;
        sp4[q] = ((const float4*)(pbase + (size_t)sh_idx[j] * NF))[f4];
    }
    for (int i = tid; i < BINSZ; i += 256) sh_na[i] = na[b * NPTS + sh_idx[i]];
    __syncthreads();

    const int rr  = r0 + lane;
    const int rcl = (rr < BINSZ) ? rr : (BINSZ - 1);   // clamp; invalid rows never write
    float4 rowr[16];
    #pragma unroll
    for (int q = 0; q < 16; ++q) rowr[q] = sp4[rcl * 16 + q];
    const float na_r = sh_na[rcl];

    float tv[TOPK]; int ti[TOPK];
    #pragma unroll
    for (int s = 0; s < TOPK; ++s) { tv[s] = FLT_MAX; ti[s] = 0; }

    // zero-fill plan: this block zero-fills rows sh_idx[r0 .. r0+vr)
    const int vr   = (r0 + 64 <= BINSZ) ? 64 : (BINSZ - r0);   // 64 or 52
    const int tot4 = vr * ROW4;                                // float4 count
    const int nst  = (tot4 + 255) / 256;                       // full-block store iters (<=313)
    const size_t obase = (size_t)b * NPTS * NPTS;
    const float4 z4 = make_float4(0.f, 0.f, 0.f, 0.f);
    int st = 0;

    const int cbase = w * 125;
    for (int jj = 0; jj < 125; ++jj) {
        // interleave 3 zero-store iterations per compute iteration (3*125 >= 313)
        #pragma unroll
        for (int u = 0; u < 3; ++u) {
            if (st < nst) {
                int idx = st * 256 + tid;
                if (idx < tot4) {
                    int r = idx / ROW4;
                    int c = idx - r * ROW4;
                    int src = sh_idx[r0 + r];
                    ((float4*)(out + obase + (size_t)src * NPTS))[c] = z4;
                }
                ++st;
            }
        }
        const int j = cbase + jj;
        const float4* cp = sp4 + j * 16;
        float acc = 0.f;
        #pragma unroll
        for (int q = 0; q < 16; ++q) {
            float4 cc = cp[q];                 // broadcast across wave
            acc += rowr[q].x * cc.x;
            acc += rowr[q].y * cc.y;
            acc += rowr[q].z * cc.z;
            acc += rowr[q].w * cc.w;
        }
        float d2 = na_r - 2.f * acc + sh_na[j];
        if (d2 < tv[TOPK - 1]) {               // keep 5 smallest d2, stable
            tv[TOPK - 1] = d2; ti[TOPK - 1] = j;
            #pragma unroll
            for (int s = TOPK - 1; s > 0; --s) {
                if (tv[s] < tv[s - 1]) {
                    float fv = tv[s]; tv[s] = tv[s - 1]; tv[s - 1] = fv;
                    int   fi = ti[s]; ti[s] = ti[s - 1]; ti[s - 1] = fi;
                }
            }
        }
    }
    // safety drain (not reachable with current constants)
    while (st < nst) {
        int idx = st * 256 + tid;
        if (idx < tot4) {
            int r = idx / ROW4;
            int c = idx - r * ROW4;
            int src = sh_idx[r0 + r];
            ((float4*)(out + obase + (size_t)src * NPTS))[c] = z4;
        }
        ++st;
    }

    #pragma unroll
    for (int s = 0; s < TOPK; ++s) { sh_mv[w][lane][s] = tv[s]; sh_mi[w][lane][s] = ti[s]; }
    __syncthreads();   // drains vmcnt: all zero stores globally visible before sparse writes

    if (tid < 64) {
        const int r = tid;
        if (r0 + r < BINSZ) {
            int h0 = 0, h1 = 0, h2 = 0, h3 = 0;
            const int src = sh_idx[r0 + r];
            float* orow = out + obase + (size_t)src * NPTS;
            #pragma unroll
            for (int s = 0; s < TOPK; ++s) {
                float v0 = sh_mv[0][r][h0];
                float v1 = sh_mv[1][r][h1];
                float v2 = sh_mv[2][r][h2];
                float v3 = sh_mv[3][r][h3];
                float best = v0; int bw = 0;
                if (v1 < best) { best = v1; bw = 1; }
                if (v2 < best) { best = v2; bw = 2; }
                if (v3 < best) { best = v3; bw = 3; }
                int j;
                if      (bw == 0) { j = sh_mi[0][r][h0]; h0++; }
                else if (bw == 1) { j = sh_mi[1][r][h1]; h1++; }
                else if (bw == 2) { j = sh_mi[2][r][h2]; h2++; }
                else              { j = sh_mi[3][r][h3]; h3++; }
                float dm  = sqrtf(fmaxf(best, 1e-6f));
                float val = expf(-0.1f * dm);
                orow[sh_idx[j]] = val;
            }
        }
    }
}

// ---------------------------------------------------------------------------
extern "C" void kernel_launch(void* const* d_in, const int* in_sizes, int n_in,
                              void* d_out, int out_size, void* d_ws, size_t ws_size,
                              hipStream_t stream) {
    const float* points = (const float*)d_in[0];
    const float* rot    = (const float*)d_in[1];
    float* out = (float*)d_out;

    int*   bin_idx = (int*)d_ws;
    float* na      = (float*)((char*)d_ws + NBATCH * NPTS * sizeof(int));
    int*   order   = (int*)((char*)d_ws + 2 * NBATCH * NPTS * sizeof(int));

    bin_norm_k<<<(NBATCH * NPTS) / 4, 256, 0, stream>>>(points, rot, bin_idx, na);
    sort_k<<<NBATCH, 256, 0, stream>>>(bin_idx, order);
    pair_topk_k<<<NBATCH * NB * 8, 256, 0, stream>>>(points, na, order, out);
}

// Round 4
// 114.173 us; speedup vs baseline: 1.0348x; 1.0348x over previous
//
#include <hip/hip_runtime.h>
#include <cfloat>
#include <cstddef>

#define NBATCH 2
#define NPTS   5000
#define NF     64
#define NB     10      // bins = N / BIN_SIZE
#define BINSZ  500
#define TOPK   5
#define ROTCOLS 100    // MAX_NUM_BINS/2 columns in rotations
#define ROW4   (NPTS / 4)   // 1250 float4 per output row

// ---------------------------------------------------------------------------
// Kernel A: per-point LSH bin + squared norm. One wave per point, 4 waves/blk.
// Rot columns staged in LDS once per block (grid-stride fill: 320 > 256!).
// ---------------------------------------------------------------------------
__global__ __launch_bounds__(256) void bin_norm_k(const float* __restrict__ pts,
                                                  const float* __restrict__ rot,
                                                  int* __restrict__ bin_idx,
                                                  float* __restrict__ na) {
    __shared__ float srot[NF * 5];
    const int t = threadIdx.x;
    for (int i = t; i < NF * 5; i += 256) {      // FIX: full 320-element fill
        int f = i / 5, h = i - 5 * f;
        srot[i] = rot[f * ROTCOLS + h];
    }
    __syncthreads();

    int pt   = blockIdx.x * 4 + (t >> 6);
    int lane = t & 63;
    float p  = pts[(size_t)pt * NF + lane];
    float nn = p * p;
    float c0 = p * srot[lane * 5 + 0];
    float c1 = p * srot[lane * 5 + 1];
    float c2 = p * srot[lane * 5 + 2];
    float c3 = p * srot[lane * 5 + 3];
    float c4 = p * srot[lane * 5 + 4];
    #pragma unroll
    for (int off = 32; off > 0; off >>= 1) {
        nn += __shfl_xor(nn, off);
        c0 += __shfl_xor(c0, off);
        c1 += __shfl_xor(c1, off);
        c2 += __shfl_xor(c2, off);
        c3 += __shfl_xor(c3, off);
        c4 += __shfl_xor(c4, off);
    }
    if (lane == 0) {
        float c[5] = {c0, c1, c2, c3, c4};
        float bv = c[0]; int bi = 0;
        #pragma unroll
        for (int h = 1; h < 5; ++h) if (c[h] > bv) { bv = c[h]; bi = h; }
        #pragma unroll
        for (int h = 0; h < 5; ++h) if (-c[h] > bv) { bv = -c[h]; bi = h + 5; }
        bin_idx[pt] = bi;   // first-max wins, matches jnp.argmax
        na[pt] = nn;
    }
}

// ---------------------------------------------------------------------------
// Kernel B: stable counting sort, fully parallelized phases.
// One block (256 threads = 4 waves) per batch.
// ---------------------------------------------------------------------------
__global__ __launch_bounds__(256) void sort_k(const int* __restrict__ bin_idx,
                                              int* __restrict__ order) {
    const int b = blockIdx.x;
    const int t = threadIdx.x;
    const int w = t >> 6, lane = t & 63;
    __shared__ int sh_bin[NPTS];
    __shared__ int sh_hist[256][NB];     // per-chunk counts -> global offsets
    __shared__ int sh_part[NB][16];      // segment partial sums
    __shared__ int sh_tot[NB + 1];       // bin starts

    for (int i = t; i < NPTS; i += 256) sh_bin[i] = bin_idx[b * NPTS + i];
    #pragma unroll
    for (int h = 0; h < NB; ++h) sh_hist[t][h] = 0;
    __syncthreads();

    const int CH = (NPTS + 255) / 256;            // 20 (last chunks short)
    const int i0 = t * CH;
    const int i1 = (i0 + CH < NPTS) ? (i0 + CH) : NPTS;
    for (int i = i0; i < i1; ++i) sh_hist[t][sh_bin[i]]++;
    __syncthreads();

    // segment partial sums: 160 threads, each sums 16 chunk-counts of one bin
    if (t < NB * 16) {
        int h = t >> 4, s = t & 15;
        int sum = 0;
        #pragma unroll
        for (int k = 0; k < 16; ++k) sum += sh_hist[s * 16 + k][h];
        sh_part[h][s] = sum;
    }
    __syncthreads();
    if (t < NB) {
        int tot = 0;
        #pragma unroll
        for (int s = 0; s < 16; ++s) tot += sh_part[t][s];
        sh_tot[t + 1] = tot;
    }
    __syncthreads();
    if (t == 0) {
        sh_tot[0] = 0;
        for (int h = 1; h <= NB; ++h) sh_tot[h] += sh_tot[h - 1];
    }
    __syncthreads();

    // per-chunk exclusive offsets: wave-parallel scan (wave w: bins w, w+4, w+8)
    for (int h = w; h < NB; h += 4) {
        int base = lane * 4;
        int v0 = sh_hist[base + 0][h];
        int v1 = sh_hist[base + 1][h];
        int v2 = sh_hist[base + 2][h];
        int v3 = sh_hist[base + 3][h];
        int lt = v0 + v1 + v2 + v3;
        int x = lt;
        #pragma unroll
        for (int off = 1; off < 64; off <<= 1) {
            int y = __shfl_up(x, off);
            if (lane >= off) x += y;
        }
        int excl = x - lt + sh_tot[h];
        sh_hist[base + 0][h] = excl;
        sh_hist[base + 1][h] = excl + v0;
        sh_hist[base + 2][h] = excl + v0 + v1;
        sh_hist[base + 3][h] = excl + v0 + v1 + v2;
    }
    __syncthreads();

    for (int i = i0; i < i1; ++i) {                // stable placement
        int h = sh_bin[i];
        order[b * NPTS + sh_hist[t][h]++] = i;
    }
}

// ---------------------------------------------------------------------------
// Kernel C: per-group pairwise d^2 + top-5 -> compact winner arrays.
// Grid: 20 groups x 8 row-blocks = 160 blocks of 256 threads.
// ---------------------------------------------------------------------------
__global__ __launch_bounds__(256) void pair_topk_k(const float* __restrict__ pts,
                                                   const float* __restrict__ na,
                                                   const int* __restrict__ order,
                                                   float* __restrict__ wv,
                                                   int* __restrict__ wd) {
    const int bx  = blockIdx.x;
    const int g   = bx >> 3;        // 0..19
    const int rb  = bx & 7;         // 0..7 (row block of 64)
    const int b   = g / NB;
    const int grp = g % NB;
    const int r0  = rb * 64;
    const int tid = threadIdx.x;
    const int w   = tid >> 6;       // col partition 0..3
    const int lane = tid & 63;      // row within block

    __shared__ float sh_pts[BINSZ * NF];     // 128000 B
    __shared__ float sh_na[BINSZ];
    __shared__ int   sh_idx[BINSZ];
    __shared__ float sh_mv[4][64][TOPK];
    __shared__ int   sh_mi[4][64][TOPK];

    const int* ord = order + b * NPTS + grp * BINSZ;
    for (int i = tid; i < BINSZ; i += 256) sh_idx[i] = ord[i];
    __syncthreads();

    const float* pbase = pts + (size_t)b * NPTS * NF;
    float4* sp4 = (float4*)sh_pts;
    for (int q = tid; q < BINSZ * (NF / 4); q += 256) {
        int j = q >> 4, f4 = q & 15;
        sp4[q] = ((const float4*)(pbase + (size_t)sh_idx[j] * NF))[f4];
    }
    for (int i = tid; i < BINSZ; i += 256) sh_na[i] = na[b * NPTS + sh_idx[i]];
    __syncthreads();

    const int rr  = r0 + lane;
    const int rcl = (rr < BINSZ) ? rr : (BINSZ - 1);   // clamp; invalid rows never write
    float4 rowr[16];
    #pragma unroll
    for (int q = 0; q < 16; ++q) rowr[q] = sp4[rcl * 16 + q];
    const float na_r = sh_na[rcl];

    float tv[TOPK]; int ti[TOPK];
    #pragma unroll
    for (int s = 0; s < TOPK; ++s) { tv[s] = FLT_MAX; ti[s] = 0; }

    const int cbase = w * 125;
    for (int jj = 0; jj < 125; ++jj) {
        const int j = cbase + jj;
        const float4* cp = sp4 + j * 16;
        float acc = 0.f;
        #pragma unroll
        for (int q = 0; q < 16; ++q) {
            float4 cc = cp[q];                 // broadcast across wave
            acc += rowr[q].x * cc.x;
            acc += rowr[q].y * cc.y;
            acc += rowr[q].z * cc.z;
            acc += rowr[q].w * cc.w;
        }
        float d2 = na_r - 2.f * acc + sh_na[j];
        if (d2 < tv[TOPK - 1]) {               // keep 5 smallest d2, stable
            tv[TOPK - 1] = d2; ti[TOPK - 1] = j;
            #pragma unroll
            for (int s = TOPK - 1; s > 0; --s) {
                if (tv[s] < tv[s - 1]) {
                    float fv = tv[s]; tv[s] = tv[s - 1]; tv[s - 1] = fv;
                    int   fi = ti[s]; ti[s] = ti[s - 1]; ti[s - 1] = fi;
                }
            }
        }
    }

    #pragma unroll
    for (int s = 0; s < TOPK; ++s) { sh_mv[w][lane][s] = tv[s]; sh_mi[w][lane][s] = ti[s]; }
    __syncthreads();

    if (tid < 64) {
        const int r = tid;
        if (r0 + r < BINSZ) {
            int h0 = 0, h1 = 0, h2 = 0, h3 = 0;
            const int src = sh_idx[r0 + r];
            const size_t gbase = ((size_t)b * NPTS + src) * TOPK;
            #pragma unroll
            for (int s = 0; s < TOPK; ++s) {
                float v0 = sh_mv[0][r][h0];
                float v1 = sh_mv[1][r][h1];
                float v2 = sh_mv[2][r][h2];
                float v3 = sh_mv[3][r][h3];
                float best = v0; int bw = 0;
                if (v1 < best) { best = v1; bw = 1; }
                if (v2 < best) { best = v2; bw = 2; }
                if (v3 < best) { best = v3; bw = 3; }
                int j;
                if      (bw == 0) { j = sh_mi[0][r][h0]; h0++; }
                else if (bw == 1) { j = sh_mi[1][r][h1]; h1++; }
                else if (bw == 2) { j = sh_mi[2][r][h2]; h2++; }
                else              { j = sh_mi[3][r][h3]; h3++; }
                float dm  = sqrtf(fmaxf(best, 1e-6f));
                wv[gbase + s] = expf(-0.1f * dm);
                wd[gbase + s] = sh_idx[j];
            }
        }
    }
}

// ---------------------------------------------------------------------------
// Kernel D: zero-fill + winner inject. 2500 blocks x 4 contiguous rows each:
// streams 200 MB of zeros at full-chip BW, then (after vmcnt-draining barrier)
// overwrites each row's 5 winner cells while the lines are L2-hot.
// ---------------------------------------------------------------------------
__global__ __launch_bounds__(256) void zero_inject_k(const float* __restrict__ wv,
                                                     const int* __restrict__ wd,
                                                     float* __restrict__ out) {
    const int t = threadIdx.x;
    const size_t gr0 = (size_t)blockIdx.x * 4;          // first of 4 global rows
    float4* o4 = ((float4*)out) + gr0 * ROW4;           // 4*1250 contiguous float4
    const float4 z4 = make_float4(0.f, 0.f, 0.f, 0.f);
    for (int i = t; i < 4 * ROW4; i += 256) o4[i] = z4;
    __syncthreads();                                    // drains vmcnt before inject
    if (t < 4 * TOPK) {
        int r = t / TOPK, s = t - r * TOPK;
        size_t g = gr0 + r;
        out[g * NPTS + wd[g * TOPK + s]] = wv[g * TOPK + s];
    }
}

// ---------------------------------------------------------------------------
extern "C" void kernel_launch(void* const* d_in, const int* in_sizes, int n_in,
                              void* d_out, int out_size, void* d_ws, size_t ws_size,
                              hipStream_t stream) {
    const float* points = (const float*)d_in[0];
    const float* rot    = (const float*)d_in[1];
    float* out = (float*)d_out;

    char* ws = (char*)d_ws;
    int*   bin_idx = (int*)ws;                                   ws += NBATCH * NPTS * sizeof(int);
    float* na      = (float*)ws;                                 ws += NBATCH * NPTS * sizeof(float);
    int*   order   = (int*)ws;                                   ws += NBATCH * NPTS * sizeof(int);
    float* wv      = (float*)ws;                                 ws += NBATCH * NPTS * TOPK * sizeof(float);
    int*   wd      = (int*)ws;

    bin_norm_k<<<(NBATCH * NPTS) / 4, 256, 0, stream>>>(points, rot, bin_idx, na);
    sort_k<<<NBATCH, 256, 0, stream>>>(bin_idx, order);
    pair_topk_k<<<NBATCH * NB * 8, 256, 0, stream>>>(points, na, order, wv, wd);
    zero_inject_k<<<(NBATCH * NPTS) / 4, 256, 0, stream>>>(wv, wd, out);
}

// Round 5
// 92.024 us; speedup vs baseline: 1.2839x; 1.2407x over previous
//
#include <hip/hip_runtime.h>
#include <cfloat>
#include <cstddef>

#define NBATCH 2
#define NPTS   5000
#define NF     64
#define NB     10      // bins = N / BIN_SIZE
#define BINSZ  500
#define TOPK   5
#define ROTCOLS 100    // MAX_NUM_BINS/2 columns in rotations

#define NCB    8                       // col-blocks per group
#define CBS    64                      // cols per col-block (last = 52)
#define NCAND  (NCB * TOPK)            // 40 candidates per row
#define NCOMP  (NBATCH * NB * NCB)     // 160 compute blocks
#define NZERO  1888                    // zero-stream blocks
#define OUT4   (NBATCH * NPTS * NPTS / 4)   // 12.5M float4 in d_out

// ---------------------------------------------------------------------------
// Kernel A: per-point LSH bin + squared norm. One wave per point, 4 waves/blk.
// ---------------------------------------------------------------------------
__global__ __launch_bounds__(256) void bin_norm_k(const float* __restrict__ pts,
                                                  const float* __restrict__ rot,
                                                  int* __restrict__ bin_idx,
                                                  float* __restrict__ na) {
    __shared__ float srot[NF * 5];
    const int t = threadIdx.x;
    for (int i = t; i < NF * 5; i += 256) {      // full 320-element fill
        int f = i / 5, h = i - 5 * f;
        srot[i] = rot[f * ROTCOLS + h];
    }
    __syncthreads();

    int pt   = blockIdx.x * 4 + (t >> 6);
    int lane = t & 63;
    float p  = pts[(size_t)pt * NF + lane];
    float nn = p * p;
    float c0 = p * srot[lane * 5 + 0];
    float c1 = p * srot[lane * 5 + 1];
    float c2 = p * srot[lane * 5 + 2];
    float c3 = p * srot[lane * 5 + 3];
    float c4 = p * srot[lane * 5 + 4];
    #pragma unroll
    for (int off = 32; off > 0; off >>= 1) {
        nn += __shfl_xor(nn, off);
        c0 += __shfl_xor(c0, off);
        c1 += __shfl_xor(c1, off);
        c2 += __shfl_xor(c2, off);
        c3 += __shfl_xor(c3, off);
        c4 += __shfl_xor(c4, off);
    }
    if (lane == 0) {
        float c[5] = {c0, c1, c2, c3, c4};
        float bv = c[0]; int bi = 0;
        #pragma unroll
        for (int h = 1; h < 5; ++h) if (c[h] > bv) { bv = c[h]; bi = h; }
        #pragma unroll
        for (int h = 0; h < 5; ++h) if (-c[h] > bv) { bv = -c[h]; bi = h + 5; }
        bin_idx[pt] = bi;   // first-max wins, matches jnp.argmax
        na[pt] = nn;
    }
}

// ---------------------------------------------------------------------------
// Kernel B: stable counting sort, fully parallelized phases.
// ---------------------------------------------------------------------------
__global__ __launch_bounds__(256) void sort_k(const int* __restrict__ bin_idx,
                                              int* __restrict__ order) {
    const int b = blockIdx.x;
    const int t = threadIdx.x;
    const int w = t >> 6, lane = t & 63;
    __shared__ int sh_bin[NPTS];
    __shared__ int sh_hist[256][NB];
    __shared__ int sh_part[NB][16];
    __shared__ int sh_tot[NB + 1];

    for (int i = t; i < NPTS; i += 256) sh_bin[i] = bin_idx[b * NPTS + i];
    #pragma unroll
    for (int h = 0; h < NB; ++h) sh_hist[t][h] = 0;
    __syncthreads();

    const int CH = (NPTS + 255) / 256;            // 20
    const int i0 = t * CH;
    const int i1 = (i0 + CH < NPTS) ? (i0 + CH) : NPTS;
    for (int i = i0; i < i1; ++i) sh_hist[t][sh_bin[i]]++;
    __syncthreads();

    if (t < NB * 16) {
        int h = t >> 4, s = t & 15;
        int sum = 0;
        #pragma unroll
        for (int k = 0; k < 16; ++k) sum += sh_hist[s * 16 + k][h];
        sh_part[h][s] = sum;
    }
    __syncthreads();
    if (t < NB) {
        int tot = 0;
        #pragma unroll
        for (int s = 0; s < 16; ++s) tot += sh_part[t][s];
        sh_tot[t + 1] = tot;
    }
    __syncthreads();
    if (t == 0) {
        sh_tot[0] = 0;
        for (int h = 1; h <= NB; ++h) sh_tot[h] += sh_tot[h - 1];
    }
    __syncthreads();

    for (int h = w; h < NB; h += 4) {
        int base = lane * 4;
        int v0 = sh_hist[base + 0][h];
        int v1 = sh_hist[base + 1][h];
        int v2 = sh_hist[base + 2][h];
        int v3 = sh_hist[base + 3][h];
        int lt = v0 + v1 + v2 + v3;
        int x = lt;
        #pragma unroll
        for (int off = 1; off < 64; off <<= 1) {
            int y = __shfl_up(x, off);
            if (lane >= off) x += y;
        }
        int excl = x - lt + sh_tot[h];
        sh_hist[base + 0][h] = excl;
        sh_hist[base + 1][h] = excl + v0;
        sh_hist[base + 2][h] = excl + v0 + v1;
        sh_hist[base + 3][h] = excl + v0 + v1 + v2;
    }
    __syncthreads();

    for (int i = i0; i < i1; ++i) {
        int h = sh_bin[i];
        order[b * NPTS + sh_hist[t][h]++] = i;
    }
}

// ---------------------------------------------------------------------------
// Kernel K3: fused {pairwise d^2 + per-colblock top-5} and {zero-stream}.
// Blocks [0,160): compute. Each block = one (group, 64-col slice); 256 threads,
//   2 rows/lane in VGPRs (rows from global/L2), cols staged in 16KB LDS.
//   LDS instr count halved vs the 1-row/lane version; only uniform broadcast
//   reads. Partial top-5 (d2, pos) per row per colblock -> compact candidates.
// Blocks [160,2048): stream zeros over d_out at full-chip BW, concurrent with
//   compute. Injection happens in the NEXT kernel (ordering by boundary).
// ---------------------------------------------------------------------------
__global__ __launch_bounds__(256) void pair_zero_k(const float* __restrict__ pts,
                                                   const float* __restrict__ na,
                                                   const int* __restrict__ order,
                                                   float* __restrict__ wv,
                                                   int* __restrict__ wd,
                                                   float* __restrict__ out) {
    const int bx  = blockIdx.x;
    const int tid = threadIdx.x;

    if (bx >= NCOMP) {                       // ---- zero-stream path ----
        const int z = bx - NCOMP;
        const int chunk = (OUT4 + NZERO - 1) / NZERO;      // 6623
        const size_t base = (size_t)z * chunk;
        size_t end = base + chunk; if (end > (size_t)OUT4) end = OUT4;
        float4* o4 = (float4*)out;
        const float4 z4 = make_float4(0.f, 0.f, 0.f, 0.f);
        for (size_t i = base + tid; i < end; i += 256) o4[i] = z4;
        return;
    }

    // ---- compute path ----
    const int g   = bx / NCB;
    const int cb  = bx - g * NCB;
    const int b   = g / NB;
    const int grp = g - b * NB;
    const int c0  = cb * CBS;
    const int ncols = (c0 + CBS <= BINSZ) ? CBS : (BINSZ - c0);   // 64 or 52

    __shared__ float sh_cols[CBS * NF];      // 16 KB
    __shared__ float sh_cna[CBS];

    const int* ord = order + b * NPTS + grp * BINSZ;
    const float4* p4 = (const float4*)(pts + (size_t)b * NPTS * NF);
    float4* sc4 = (float4*)sh_cols;

    for (int i = tid; i < ncols * 16; i += 256) {
        int c = i >> 4, q = i & 15;
        sc4[c * 16 + q] = p4[(size_t)ord[c0 + c] * 16 + q];
    }
    if (tid < ncols) sh_cna[tid] = na[b * NPTS + ord[c0 + tid]];
    __syncthreads();

    const int p0 = tid, p1 = tid + 256;
    const bool h1 = (p1 < BINSZ);            // threads 0..243 own a 2nd row
    const int gi0 = ord[p0];
    const int gi1 = h1 ? ord[p1] : gi0;
    float4 r0[16], r1[16];
    #pragma unroll
    for (int q = 0; q < 16; ++q) {
        r0[q] = p4[(size_t)gi0 * 16 + q];
        r1[q] = p4[(size_t)gi1 * 16 + q];
    }
    const float na0 = na[b * NPTS + gi0];
    const float na1 = na[b * NPTS + gi1];

    float tv0[TOPK], tv1[TOPK]; int tp0[TOPK], tp1[TOPK];
    #pragma unroll
    for (int s = 0; s < TOPK; ++s) { tv0[s] = FLT_MAX; tv1[s] = FLT_MAX; tp0[s] = 0; tp1[s] = 0; }

    for (int c = 0; c < ncols; ++c) {
        const float4* cq = sc4 + c * 16;     // wave-uniform broadcast reads
        float a0 = 0.f, a1 = 0.f;
        #pragma unroll
        for (int q = 0; q < 16; ++q) {       // identical accumulation order to r4
            float4 cc = cq[q];
            a0 += r0[q].x * cc.x; a0 += r0[q].y * cc.y;
            a0 += r0[q].z * cc.z; a0 += r0[q].w * cc.w;
            a1 += r1[q].x * cc.x; a1 += r1[q].y * cc.y;
            a1 += r1[q].z * cc.z; a1 += r1[q].w * cc.w;
        }
        const float cna = sh_cna[c];
        const int pos = c0 + c;
        float d0 = na0 - 2.f * a0 + cna;
        float d1 = na1 - 2.f * a1 + cna;
        if (d0 < tv0[TOPK - 1]) {            // strict <: ties keep earlier pos
            tv0[TOPK - 1] = d0; tp0[TOPK - 1] = pos;
            #pragma unroll
            for (int s = TOPK - 1; s > 0; --s) {
                if (tv0[s] < tv0[s - 1]) {
                    float fv = tv0[s]; tv0[s] = tv0[s - 1]; tv0[s - 1] = fv;
                    int   fi = tp0[s]; tp0[s] = tp0[s - 1]; tp0[s - 1] = fi;
                }
            }
        }
        if (h1 && d1 < tv1[TOPK - 1]) {
            tv1[TOPK - 1] = d1; tp1[TOPK - 1] = pos;
            #pragma unroll
            for (int s = TOPK - 1; s > 0; --s) {
                if (tv1[s] < tv1[s - 1]) {
                    float fv = tv1[s]; tv1[s] = tv1[s - 1]; tv1[s - 1] = fv;
                    int   fi = tp1[s]; tp1[s] = tp1[s - 1]; tp1[s - 1] = fi;
                }
            }
        }
    }

    const int slotbase = (b * NB + grp) * BINSZ;
    {
        size_t wbase = ((size_t)(slotbase + p0) * NCB + cb) * TOPK;
        #pragma unroll
        for (int s = 0; s < TOPK; ++s) { wv[wbase + s] = tv0[s]; wd[wbase + s] = tp0[s]; }
    }
    if (h1) {
        size_t wbase = ((size_t)(slotbase + p1) * NCB + cb) * TOPK;
        #pragma unroll
        for (int s = 0; s < TOPK; ++s) { wv[wbase + s] = tv1[s]; wd[wbase + s] = tp1[s]; }
    }
}

// ---------------------------------------------------------------------------
// Kernel M: per-row merge of 8 partial top-5 lists by exact (d2, pos)
// lexicographic order (== single-scan selection), then exp + inject into the
// already-zeroed d_out. One thread per row-slot; candidate reads contiguous.
// ---------------------------------------------------------------------------
__global__ __launch_bounds__(256) void merge_inject_k(const float* __restrict__ wv,
                                                      const int* __restrict__ wd,
                                                      const int* __restrict__ order,
                                                      float* __restrict__ out) {
    const int slot = blockIdx.x * 256 + threadIdx.x;
    if (slot >= NBATCH * NPTS) return;
    const int b   = slot / (NB * BINSZ);
    const int rem = slot - b * NB * BINSZ;
    const int grp = rem / BINSZ;
    const int p   = rem - grp * BINSZ;
    const int* ord = order + b * NPTS + grp * BINSZ;
    const int src = ord[p];

    float cv[NCAND]; int cp[NCAND];
    const size_t base = (size_t)slot * NCAND;
    #pragma unroll
    for (int k = 0; k < NCAND; ++k) { cv[k] = wv[base + k]; cp[k] = wd[base + k]; }

    unsigned long long used = 0;
    float* orow = out + ((size_t)b * NPTS + src) * NPTS;
    #pragma unroll
    for (int s = 0; s < TOPK; ++s) {
        float bv = FLT_MAX; int bp = 0x7fffffff; int bk = 0;
        #pragma unroll
        for (int k = 0; k < NCAND; ++k) {
            bool ok = !((used >> k) & 1ull);
            bool better = ok && ((cv[k] < bv) || (cv[k] == bv && cp[k] < bp));
            if (better) { bv = cv[k]; bp = cp[k]; bk = k; }
        }
        used |= (1ull << bk);
        float val = expf(-0.1f * sqrtf(fmaxf(bv, 1e-6f)));
        orow[ord[bp]] = val;
    }
}

// ---------------------------------------------------------------------------
extern "C" void kernel_launch(void* const* d_in, const int* in_sizes, int n_in,
                              void* d_out, int out_size, void* d_ws, size_t ws_size,
                              hipStream_t stream) {
    const float* points = (const float*)d_in[0];
    const float* rot    = (const float*)d_in[1];
    float* out = (float*)d_out;

    char* ws = (char*)d_ws;
    int*   bin_idx = (int*)ws;   ws += NBATCH * NPTS * sizeof(int);
    float* na      = (float*)ws; ws += NBATCH * NPTS * sizeof(float);
    int*   order   = (int*)ws;   ws += NBATCH * NPTS * sizeof(int);
    float* wv      = (float*)ws; ws += (size_t)NBATCH * NPTS * NCAND * sizeof(float);
    int*   wd      = (int*)ws;   // + 1.6 MB -> total ws use ~3.4 MB

    bin_norm_k<<<(NBATCH * NPTS) / 4, 256, 0, stream>>>(points, rot, bin_idx, na);
    sort_k<<<NBATCH, 256, 0, stream>>>(bin_idx, order);
    pair_zero_k<<<NCOMP + NZERO, 256, 0, stream>>>(points, na, order, wv, wd, out);
    merge_inject_k<<<(NBATCH * NPTS + 255) / 256, 256, 0, stream>>>(wv, wd, order, out);
}